// Round 9
// baseline (101.345 us; speedup 1.0000x reference)
//
#include <hip/hip_runtime.h>

// Problem: N=64 graphs, K=64 nodes, C_IN=128, C=128, fp32.
// Single kernel, per-graph producer/consumer sync (NO global barrier):
// grid (64 graphs, 12 roles); all 12 blocks of graph g share an XCD
// (linear_id%8 == g%8 heuristic -> L2-local h/T/S'), correctness via
// agent-scope release/acquire atomics on per-graph counters (c1, c2).
//   P0 (j<8):  h[:,16j:16j+16] = x@W_lin_slice.T + b_lin + t*W_lin[:,128]
//   P2 (j<8):  binary: A=h@Wb1L.T, Bb=h@Wb1R.T+bb1 (LDS only);
//              U=exp2(kA), V=exp2(kBb); S'=(63-2*sum_{i!=j}rcp(U_j V_i+1))/64
//      (j>=8): unary: T = tanh(h@Wu1.T + bu1)
//   P3 (j<8):  out[:,16j:16j+16] = T@Wu2s.T + S'@Wb2s.T + bu2 + (63/64)bb2
// Counters zeroed each call by hipMemsetAsync (graph-capture-safe).
#define LS 132  // LDS row stride (dwords): (4l)%32 -> 8 dwords/bank for b128
#define USTR 20 // U/V row stride: (20l)%32 -> 8 dwords/bank
#define ROW_ELEMS 524288  // 4096*128
#define EXPC 2.8853900817779268f  // 2*log2(e)

__device__ __forceinline__ float tanh_fast(float x) {
    float e = __builtin_amdgcn_exp2f(x * EXPC);
    return 1.0f - 2.0f * __builtin_amdgcn_rcpf(e + 1.0f);
}

__device__ __forceinline__ void stage64(const float* __restrict__ X, int r0,
                                        float* __restrict__ xs, int tid) {
    const float4* src = reinterpret_cast<const float4*>(X + (size_t)r0 * 128);
#pragma unroll
    for (int p = 0; p < 8; ++p) {
        const int q = p * 256 + tid;  // 2048 float4s
        const int r = q >> 5;
        const int k4 = (q & 31) << 2;
        *reinterpret_cast<float4*>(&xs[r * LS + k4]) = src[q];
    }
}

template <int NC>
__device__ __forceinline__ void accum_lds(const float* __restrict__ xs,
                                          const float* __restrict__ wt,
                                          int lane, int wc0,
                                          float (&acc)[NC]) {
#pragma unroll 8
    for (int kq = 0; kq < 32; ++kq) {
        const float4 a =
            *reinterpret_cast<const float4*>(&xs[lane * LS + kq * 4]);
#pragma unroll
        for (int c = 0; c < NC; ++c) {
            const float4 w = *reinterpret_cast<const float4*>(
                &wt[(wc0 + c) * 128 + kq * 4]);
            acc[c] = fmaf(a.x, w.x, acc[c]);
            acc[c] = fmaf(a.y, w.y, acc[c]);
            acc[c] = fmaf(a.z, w.z, acc[c]);
            acc[c] = fmaf(a.w, w.w, acc[c]);
        }
    }
}

__global__ __launch_bounds__(256) void megakernel(
    const float* __restrict__ tp, const float* __restrict__ x,
    const float* __restrict__ W_lin, const float* __restrict__ b_lin,
    const float* __restrict__ Wu1, const float* __restrict__ bu1,
    const float* __restrict__ Wu2, const float* __restrict__ bu2,
    const float* __restrict__ Wb1, const float* __restrict__ bb1,
    const float* __restrict__ Wb2, const float* __restrict__ bb2,
    float* __restrict__ h, float* __restrict__ T, float* __restrict__ S,
    float* __restrict__ out, unsigned int* __restrict__ cnt) {
    __shared__ float smem[64 * LS + 32 * 128];
    float* xs = smem;
    float* wt = smem + 64 * LS;
    float* us = smem;              // alias: xs region (dead between uses)
    float* vs = smem + 64 * USTR;
    const int tid = threadIdx.x;
    const int lane = tid & 63;
    const int wv = __builtin_amdgcn_readfirstlane(tid >> 6);
    const int g = blockIdx.x;   // graph
    const int j = blockIdx.y;   // role 0..11
    const int r0 = g * 64;
    unsigned int* c1 = cnt + g;
    unsigned int* c2 = cnt + 64 + g;

    // ---------------- P0: h producers (j < 8) ----------------
    if (j < 8) {
        stage64(x, r0, xs, tid);
        // W_lin rows 16j..16j+16 (row stride 129, odd): scalar-coalesced
#pragma unroll
        for (int p = 0; p < 8; ++p) {
            const int q = p * 256 + tid;  // 2048 floats = 16*128
            const int row = q >> 7;
            const int col = q & 127;
            wt[row * 128 + col] = W_lin[(j * 16 + row) * 129 + col];
        }
        __syncthreads();
        float acc[4] = {0.f, 0.f, 0.f, 0.f};
        accum_lds<4>(xs, wt, lane, wv * 4, acc);
        const int c0 = j * 16 + wv * 4;
        const float tv = tp[0];
        float4 o;
        o.x = acc[0] + b_lin[c0 + 0] + tv * W_lin[(c0 + 0) * 129 + 128];
        o.y = acc[1] + b_lin[c0 + 1] + tv * W_lin[(c0 + 1) * 129 + 128];
        o.z = acc[2] + b_lin[c0 + 2] + tv * W_lin[(c0 + 2) * 129 + 128];
        o.w = acc[3] + b_lin[c0 + 3] + tv * W_lin[(c0 + 3) * 129 + 128];
        *reinterpret_cast<float4*>(&h[(size_t)(r0 + lane) * 128 + c0]) = o;
        __syncthreads();  // drains vmcnt -> h stores in L2; wt reads done
        if (tid == 0)
            __hip_atomic_fetch_add(c1, 1u, __ATOMIC_RELEASE,
                                   __HIP_MEMORY_SCOPE_AGENT);
    }

    // ---- Prestage P2 weights (overlaps the c1 spin) ----
    {
        const int cb = j < 8 ? j * 16 : 0;
        const int cg0 = j >= 8 ? (j - 8) * 32 : 0;
#pragma unroll
        for (int p = 0; p < 4; ++p) {
            const int q = p * 256 + tid;  // 1024 float4s
            const int row = q >> 5;
            const int k4 = (q & 31) << 2;
            const float* src;
            if (j < 8)
                src = (row < 16) ? (Wb1 + (cb + row) * 256 + k4)
                                 : (Wb1 + (cb + row - 16) * 256 + 128 + k4);
            else
                src = Wu1 + (cg0 + row) * 128 + k4;
            *reinterpret_cast<float4*>(&wt[row * 128 + k4]) =
                *reinterpret_cast<const float4*>(src);
        }
    }
    if (tid == 0) {
        while (__hip_atomic_load(c1, __ATOMIC_ACQUIRE,
                                 __HIP_MEMORY_SCOPE_AGENT) < 8u)
            __builtin_amdgcn_s_sleep(1);
    }
    __syncthreads();   // h ready (acquire by tid0 + block barrier)
    stage64(h, r0, xs, tid);
    __syncthreads();

    // ---------------- P2 ----------------
    if (j < 8) {  // ---- binary chunk of 16 channels ----
        const int cb = j * 16;
        const bool isB = wv >= 2;
        const int half = wv & 1;
        const int c0 = cb + half * 8;
        const int wc0 = (isB ? 16 : 0) + half * 8;
        float acc[8] = {0.f, 0.f, 0.f, 0.f, 0.f, 0.f, 0.f, 0.f};
        accum_lds<8>(xs, wt, lane, wc0, acc);
        float e[8];
#pragma unroll
        for (int c = 0; c < 8; ++c) {
            const float v = isB ? (acc[c] + bb1[c0 + c]) : acc[c];
            e[c] = __builtin_amdgcn_exp2f(v * EXPC);
        }
        __syncthreads();  // all waves done reading xs/wt
        float* dstl = (isB ? vs : us) + lane * USTR + half * 8;
        *reinterpret_cast<float4*>(dstl) = make_float4(e[0], e[1], e[2], e[3]);
        *reinterpret_cast<float4*>(dstl + 4) =
            make_float4(e[4], e[5], e[6], e[7]);
        __syncthreads();

        const int lc = wv * 4;
        const float4 u =
            *reinterpret_cast<const float4*>(&us[lane * USTR + lc]);
        float s0 = 0.f, s1 = 0.f, s2 = 0.f, s3 = 0.f;
#pragma unroll 8
        for (int i = 0; i < 64; ++i) {
            const float4 v =
                *reinterpret_cast<const float4*>(&vs[i * USTR + lc]);
            s0 += __builtin_amdgcn_rcpf(fmaf(u.x, v.x, 1.0f));
            s1 += __builtin_amdgcn_rcpf(fmaf(u.y, v.y, 1.0f));
            s2 += __builtin_amdgcn_rcpf(fmaf(u.z, v.z, 1.0f));
            s3 += __builtin_amdgcn_rcpf(fmaf(u.w, v.w, 1.0f));
        }
        const float4 vj =
            *reinterpret_cast<const float4*>(&vs[lane * USTR + lc]);
        float4 o;
        o.x = (63.0f - 2.0f * (s0 - __builtin_amdgcn_rcpf(fmaf(u.x, vj.x, 1.0f)))) * 0.015625f;
        o.y = (63.0f - 2.0f * (s1 - __builtin_amdgcn_rcpf(fmaf(u.y, vj.y, 1.0f)))) * 0.015625f;
        o.z = (63.0f - 2.0f * (s2 - __builtin_amdgcn_rcpf(fmaf(u.z, vj.z, 1.0f)))) * 0.015625f;
        o.w = (63.0f - 2.0f * (s3 - __builtin_amdgcn_rcpf(fmaf(u.w, vj.w, 1.0f)))) * 0.015625f;
        *reinterpret_cast<float4*>(&S[(size_t)(r0 + lane) * 128 + cb + lc]) = o;
    } else {  // ---- unary T ----
        const int c0 = (j - 8) * 32 + wv * 8;
        float acc[8] = {0.f, 0.f, 0.f, 0.f, 0.f, 0.f, 0.f, 0.f};
        accum_lds<8>(xs, wt, lane, wv * 8, acc);
        float4 v0, v1;
        v0.x = tanh_fast(acc[0] + bu1[c0 + 0]);
        v0.y = tanh_fast(acc[1] + bu1[c0 + 1]);
        v0.z = tanh_fast(acc[2] + bu1[c0 + 2]);
        v0.w = tanh_fast(acc[3] + bu1[c0 + 3]);
        v1.x = tanh_fast(acc[4] + bu1[c0 + 4]);
        v1.y = tanh_fast(acc[5] + bu1[c0 + 5]);
        v1.z = tanh_fast(acc[6] + bu1[c0 + 6]);
        v1.w = tanh_fast(acc[7] + bu1[c0 + 7]);
        float* dst = T + (size_t)(r0 + lane) * 128 + c0;
        *reinterpret_cast<float4*>(dst) = v0;
        *reinterpret_cast<float4*>(dst + 4) = v1;
    }
    __syncthreads();  // drains vmcnt -> T/S' stores in L2
    if (tid == 0)
        __hip_atomic_fetch_add(c2, 1u, __ATOMIC_RELEASE,
                               __HIP_MEMORY_SCOPE_AGENT);

    // ---------------- P3: out (j < 8) ----------------
    if (j < 8) {
        const int cb = j * 16;
        // Prestage Wu2/Wb2 slices (overlaps the c2 spin)
#pragma unroll
        for (int p = 0; p < 4; ++p) {
            const int q = p * 256 + tid;  // 1024 float4s
            const int row = q >> 5;
            const int k4 = (q & 31) << 2;
            const float* src = (row < 16)
                                   ? (Wu2 + (cb + row) * 128 + k4)
                                   : (Wb2 + (cb + row - 16) * 128 + k4);
            *reinterpret_cast<float4*>(&wt[row * 128 + k4]) =
                *reinterpret_cast<const float4*>(src);
        }
        if (tid == 0) {
            while (__hip_atomic_load(c2, __ATOMIC_ACQUIRE,
                                     __HIP_MEMORY_SCOPE_AGENT) < 12u)
                __builtin_amdgcn_s_sleep(1);
        }
        __syncthreads();  // T/S' ready
        stage64(T, r0, xs, tid);
        __syncthreads();
        float acc[4] = {0.f, 0.f, 0.f, 0.f};
        accum_lds<4>(xs, wt, lane, wv * 4, acc);
        __syncthreads();  // done reading T tile
        stage64(S, r0, xs, tid);
        __syncthreads();
        accum_lds<4>(xs, wt, lane, 16 + wv * 4, acc);
        const int c0 = cb + wv * 4;
        float4 o;
        o.x = acc[0] + bu2[c0 + 0] + 0.984375f * bb2[c0 + 0];
        o.y = acc[1] + bu2[c0 + 1] + 0.984375f * bb2[c0 + 1];
        o.z = acc[2] + bu2[c0 + 2] + 0.984375f * bb2[c0 + 2];
        o.w = acc[3] + bu2[c0 + 3] + 0.984375f * bb2[c0 + 3];
        *reinterpret_cast<float4*>(&out[(size_t)(r0 + lane) * 128 + c0]) = o;
    }
}

extern "C" void kernel_launch(void* const* d_in, const int* in_sizes, int n_in,
                              void* d_out, int out_size, void* d_ws,
                              size_t ws_size, hipStream_t stream) {
    const float* t = (const float*)d_in[0];
    const float* x = (const float*)d_in[1];
    const float* W_lin = (const float*)d_in[2];
    const float* b_lin = (const float*)d_in[3];
    const float* Wu1 = (const float*)d_in[4];
    const float* bu1 = (const float*)d_in[5];
    const float* Wu2 = (const float*)d_in[6];
    const float* bu2 = (const float*)d_in[7];
    const float* Wb1 = (const float*)d_in[8];
    const float* bb1 = (const float*)d_in[9];
    const float* Wb2 = (const float*)d_in[10];
    const float* bb2 = (const float*)d_in[11];
    float* out = (float*)d_out;

    float* ws = (float*)d_ws;
    float* h = ws;
    float* T = ws + 1 * ROW_ELEMS;
    float* S = ws + 2 * ROW_ELEMS;
    unsigned int* cnt = (unsigned int*)(ws + 3 * ROW_ELEMS);

    // Zero the 128 per-graph counters (c1[64], c2[64]); captures as a
    // memset node, runs before the kernel on this stream each replay.
    hipMemsetAsync(cnt, 0, 128 * sizeof(unsigned int), stream);
    megakernel<<<dim3(64, 12), 256, 0, stream>>>(
        t, x, W_lin, b_lin, Wu1, bu1, Wu2, bu2, Wb1, bb1, Wb2, bb2, h, T, S,
        out, cnt);
    (void)in_sizes; (void)n_in; (void)out_size; (void)ws_size;
}

// Round 10
// 37.810 us; speedup vs baseline: 2.6804x; 2.6804x over previous
//
#include <hip/hip_runtime.h>

// Problem: N=64 graphs, K=64 nodes, C_IN=128, C=128, fp32.
// R8 structure (3 kernels, XCD-local: blockIdx.x = graph so linear_id%8 ==
// g%8 -> all blocks of a graph share one XCD's L2 for h/T/S') with ALL
// GEMM weights LDS-staged (wave-uniform broadcast reads; no s_load batches).
//   K1: h = x @ W_lin[:, :128].T + b_lin + t*W_lin[:,128]
//   K2f: binary blocks: A=h@Wb1L.T, Bb=h@Wb1R.T+bb1 (LDS only);
//          U=exp2(kA), V=exp2(kBb); S'=(63-2*sum_{i!=j}rcp(U_j V_i+1))/64
//        unary blocks: T = tanh(h@Wu1.T + bu1)
//   K4: out = T@Wu2.T + S'@Wb2.T + bu2 + (63/64)*bb2
#define LS 132  // LDS row stride (dwords): (4l)%32 -> 8 dwords/bank for b128
#define USTR 20 // U/V row stride: (20l)%32 -> 8 dwords/bank
#define ROW_ELEMS 524288  // 4096*128
#define EXPC 2.8853900817779268f  // 2*log2(e)

__device__ __forceinline__ float tanh_fast(float x) {
    float e = __builtin_amdgcn_exp2f(x * EXPC);
    return 1.0f - 2.0f * __builtin_amdgcn_rcpf(e + 1.0f);
}

__device__ __forceinline__ void stage64(const float* __restrict__ X, int r0,
                                        float* __restrict__ xs, int tid) {
    const float4* src = reinterpret_cast<const float4*>(X + (size_t)r0 * 128);
#pragma unroll
    for (int p = 0; p < 8; ++p) {
        const int q = p * 256 + tid;  // 2048 float4s
        const int r = q >> 5;
        const int k4 = (q & 31) << 2;
        *reinterpret_cast<float4*>(&xs[r * LS + k4]) = src[q];
    }
}

template <int NC>
__device__ __forceinline__ void accum_lds(const float* __restrict__ xs,
                                          const float* __restrict__ wt,
                                          int lane, int wc0,
                                          float (&acc)[NC]) {
#pragma unroll 8
    for (int kq = 0; kq < 32; ++kq) {
        const float4 a =
            *reinterpret_cast<const float4*>(&xs[lane * LS + kq * 4]);
#pragma unroll
        for (int c = 0; c < NC; ++c) {
            const float4 w = *reinterpret_cast<const float4*>(
                &wt[(wc0 + c) * 128 + kq * 4]);
            acc[c] = fmaf(a.x, w.x, acc[c]);
            acc[c] = fmaf(a.y, w.y, acc[c]);
            acc[c] = fmaf(a.z, w.z, acc[c]);
            acc[c] = fmaf(a.w, w.w, acc[c]);
        }
    }
}

// K1: h = x@W_lin[:,:128].T + b_lin + t*W_lin[:,128]. grid (64,16):
// bx = graph, 8 cols/block (2/wave). LDS 37.8 KB -> 4 blocks/CU (1024 blocks
// all resident). Weights LDS-staged (odd 129 stride -> scalar-coalesced).
__global__ __launch_bounds__(256) void k1_h(const float* __restrict__ x,
                                            const float* __restrict__ W_lin,
                                            const float* __restrict__ b_lin,
                                            const float* __restrict__ tp,
                                            float* __restrict__ h) {
    __shared__ float xs[64 * LS];
    __shared__ float wt[8 * 128];
    const int tid = threadIdx.x;
    const int lane = tid & 63;
    const int wv = __builtin_amdgcn_readfirstlane(tid >> 6);
    const int r0 = blockIdx.x * 64;       // graph
    const int cb = blockIdx.y * 8;        // col base
    stage64(x, r0, xs, tid);
#pragma unroll
    for (int p = 0; p < 4; ++p) {         // 1024 floats = 8 rows x 128
        const int q = p * 256 + tid;
        const int row = q >> 7;
        const int col = q & 127;
        wt[row * 128 + col] = W_lin[(cb + row) * 129 + col];
    }
    __syncthreads();
    float acc[2] = {0.f, 0.f};
    accum_lds<2>(xs, wt, lane, wv * 2, acc);
    const int c0 = cb + wv * 2;
    const float tv = tp[0];
    float2 o;
    o.x = acc[0] + b_lin[c0 + 0] + tv * W_lin[(c0 + 0) * 129 + 128];
    o.y = acc[1] + b_lin[c0 + 1] + tv * W_lin[(c0 + 1) * 129 + 128];
    *reinterpret_cast<float2*>(&h[(size_t)(r0 + lane) * 128 + c0]) = o;
}

// K2f: grid (64, 12): bx = graph. by < 8 -> binary chunk of 16 channels;
// by >= 8 -> unary T cols (32/block, 8/wave). LDS 50.2 KB -> 3 blocks/CU.
__global__ __launch_bounds__(256) void k2_fused(
    const float* __restrict__ h, const float* __restrict__ Wu1,
    const float* __restrict__ bu1, const float* __restrict__ Wb1,
    const float* __restrict__ bb1, float* __restrict__ T,
    float* __restrict__ S) {
    __shared__ float smem[64 * LS + 32 * 128];
    float* xs = smem;
    float* wt = smem + 64 * LS;
    float* us = smem;              // alias: xs region (dead after GEMM)
    float* vs = smem + 64 * USTR;
    const int tid = threadIdx.x;
    const int lane = tid & 63;
    const int wv = __builtin_amdgcn_readfirstlane(tid >> 6);
    const int r0 = blockIdx.x * 64;  // graph * 64
    const int j = blockIdx.y;        // role 0..11
    stage64(h, r0, xs, tid);
    {   // Stage 32 weight rows (binary: 16 A-rows + 16 B-rows; unary: 32 Wu1)
        const int cb = j < 8 ? j * 16 : 0;
        const int cg0 = j >= 8 ? (j - 8) * 32 : 0;
#pragma unroll
        for (int p = 0; p < 4; ++p) {
            const int q = p * 256 + tid;  // 1024 float4s
            const int row = q >> 5;
            const int k4 = (q & 31) << 2;
            const float* src;
            if (j < 8)
                src = (row < 16) ? (Wb1 + (cb + row) * 256 + k4)
                                 : (Wb1 + (cb + row - 16) * 256 + 128 + k4);
            else
                src = Wu1 + (cg0 + row) * 128 + k4;
            *reinterpret_cast<float4*>(&wt[row * 128 + k4]) =
                *reinterpret_cast<const float4*>(src);
        }
    }
    __syncthreads();

    if (j < 8) {  // ---- binary chunk ----
        const int cb = j * 16;
        const bool isB = wv >= 2;
        const int half = wv & 1;
        const int c0 = cb + half * 8;
        const int wc0 = (isB ? 16 : 0) + half * 8;
        float acc[8] = {0.f, 0.f, 0.f, 0.f, 0.f, 0.f, 0.f, 0.f};
        accum_lds<8>(xs, wt, lane, wc0, acc);
        float e[8];
#pragma unroll
        for (int c = 0; c < 8; ++c) {
            const float v = isB ? (acc[c] + bb1[c0 + c]) : acc[c];
            e[c] = __builtin_amdgcn_exp2f(v * EXPC);
        }
        __syncthreads();  // all waves done reading xs; safe to overwrite
        float* dstl = (isB ? vs : us) + lane * USTR + half * 8;
        *reinterpret_cast<float4*>(dstl) = make_float4(e[0], e[1], e[2], e[3]);
        *reinterpret_cast<float4*>(dstl + 4) =
            make_float4(e[4], e[5], e[6], e[7]);
        __syncthreads();

        const int lc = wv * 4;
        const float4 u =
            *reinterpret_cast<const float4*>(&us[lane * USTR + lc]);
        float s0 = 0.f, s1 = 0.f, s2 = 0.f, s3 = 0.f;
#pragma unroll 8
        for (int i = 0; i < 64; ++i) {
            const float4 v =
                *reinterpret_cast<const float4*>(&vs[i * USTR + lc]);
            s0 += __builtin_amdgcn_rcpf(fmaf(u.x, v.x, 1.0f));
            s1 += __builtin_amdgcn_rcpf(fmaf(u.y, v.y, 1.0f));
            s2 += __builtin_amdgcn_rcpf(fmaf(u.z, v.z, 1.0f));
            s3 += __builtin_amdgcn_rcpf(fmaf(u.w, v.w, 1.0f));
        }
        const float4 vj =
            *reinterpret_cast<const float4*>(&vs[lane * USTR + lc]);
        float4 o;
        o.x = (63.0f - 2.0f * (s0 - __builtin_amdgcn_rcpf(fmaf(u.x, vj.x, 1.0f)))) * 0.015625f;
        o.y = (63.0f - 2.0f * (s1 - __builtin_amdgcn_rcpf(fmaf(u.y, vj.y, 1.0f)))) * 0.015625f;
        o.z = (63.0f - 2.0f * (s2 - __builtin_amdgcn_rcpf(fmaf(u.z, vj.z, 1.0f)))) * 0.015625f;
        o.w = (63.0f - 2.0f * (s3 - __builtin_amdgcn_rcpf(fmaf(u.w, vj.w, 1.0f)))) * 0.015625f;
        *reinterpret_cast<float4*>(&S[(size_t)(r0 + lane) * 128 + cb + lc]) = o;
    } else {  // ---- unary T ----
        const int c0 = (j - 8) * 32 + wv * 8;
        float acc[8] = {0.f, 0.f, 0.f, 0.f, 0.f, 0.f, 0.f, 0.f};
        accum_lds<8>(xs, wt, lane, wv * 8, acc);
        float4 v0, v1;
        v0.x = tanh_fast(acc[0] + bu1[c0 + 0]);
        v0.y = tanh_fast(acc[1] + bu1[c0 + 1]);
        v0.z = tanh_fast(acc[2] + bu1[c0 + 2]);
        v0.w = tanh_fast(acc[3] + bu1[c0 + 3]);
        v1.x = tanh_fast(acc[4] + bu1[c0 + 4]);
        v1.y = tanh_fast(acc[5] + bu1[c0 + 5]);
        v1.z = tanh_fast(acc[6] + bu1[c0 + 6]);
        v1.w = tanh_fast(acc[7] + bu1[c0 + 7]);
        float* dst = T + (size_t)(r0 + lane) * 128 + c0;
        *reinterpret_cast<float4*>(dst) = v0;
        *reinterpret_cast<float4*>(dst + 4) = v1;
    }
}

// K4: out = T@Wu2.T + S'@Wb2.T + bu2 + (63/64)*bb2. grid (64,16):
// bx = graph, 8 cols/block (2/wave). wt = [Wu2 8 rows | Wb2 8 rows] staged
// once (float4); two sequential 128-k passes over one xs tile.
// LDS 41.8 KB -> 3 blocks/CU.
__global__ __launch_bounds__(256) void k4_out(
    const float* __restrict__ T, const float* __restrict__ S,
    const float* __restrict__ Wu2, const float* __restrict__ Wb2,
    const float* __restrict__ bu2, const float* __restrict__ bb2,
    float* __restrict__ out) {
    __shared__ float xs[64 * LS];
    __shared__ float wt[16 * 128];
    const int tid = threadIdx.x;
    const int lane = tid & 63;
    const int wv = __builtin_amdgcn_readfirstlane(tid >> 6);
    const int r0 = blockIdx.x * 64;
    const int cb = blockIdx.y * 8;
    stage64(T, r0, xs, tid);
#pragma unroll
    for (int p = 0; p < 2; ++p) {  // 512 float4s = 16 rows x 128
        const int q = p * 256 + tid;
        const int row = q >> 5;
        const int k4 = (q & 31) << 2;
        const float* src = (row < 8) ? (Wu2 + (cb + row) * 128 + k4)
                                     : (Wb2 + (cb + row - 8) * 128 + k4);
        *reinterpret_cast<float4*>(&wt[row * 128 + k4]) =
            *reinterpret_cast<const float4*>(src);
    }
    __syncthreads();
    float acc[2] = {0.f, 0.f};
    accum_lds<2>(xs, wt, lane, wv * 2, acc);
    __syncthreads();  // done reading T tile
    stage64(S, r0, xs, tid);
    __syncthreads();
    accum_lds<2>(xs, wt, lane, 8 + wv * 2, acc);
    const int c0 = cb + wv * 2;
    float2 o;
    o.x = acc[0] + bu2[c0 + 0] + 0.984375f * bb2[c0 + 0];
    o.y = acc[1] + bu2[c0 + 1] + 0.984375f * bb2[c0 + 1];
    *reinterpret_cast<float2*>(&out[(size_t)(r0 + lane) * 128 + c0]) = o;
}

extern "C" void kernel_launch(void* const* d_in, const int* in_sizes, int n_in,
                              void* d_out, int out_size, void* d_ws,
                              size_t ws_size, hipStream_t stream) {
    const float* t = (const float*)d_in[0];
    const float* x = (const float*)d_in[1];
    const float* W_lin = (const float*)d_in[2];
    const float* b_lin = (const float*)d_in[3];
    const float* Wu1 = (const float*)d_in[4];
    const float* bu1 = (const float*)d_in[5];
    const float* Wu2 = (const float*)d_in[6];
    const float* bu2 = (const float*)d_in[7];
    const float* Wb1 = (const float*)d_in[8];
    const float* bb1 = (const float*)d_in[9];
    const float* Wb2 = (const float*)d_in[10];
    const float* bb2 = (const float*)d_in[11];
    float* out = (float*)d_out;

    float* ws = (float*)d_ws;
    float* h = ws;
    float* T = ws + 1 * ROW_ELEMS;
    float* S = ws + 2 * ROW_ELEMS;

    // All grids: blockIdx.x = graph -> linear_id % 8 == graph % 8 (XCD-local).
    k1_h<<<dim3(64, 16), 256, 0, stream>>>(x, W_lin, b_lin, t, h);
    k2_fused<<<dim3(64, 12), 256, 0, stream>>>(h, Wu1, bu1, Wb1, bb1, T, S);
    k4_out<<<dim3(64, 16), 256, 0, stream>>>(T, S, Wu2, Wb2, bu2, bb2, out);
    (void)in_sizes; (void)n_in; (void)out_size; (void)ws_size;
}

// Round 11
// 37.367 us; speedup vs baseline: 2.7121x; 1.0118x over previous
//
#include <hip/hip_runtime.h>

// Problem: N=64 graphs, K=64 nodes, C_IN=128, C=128, fp32.
// 3 kernels, XCD-local (blockIdx.x = graph -> linear_id%8 == g%8: all blocks
// of a graph share one XCD's L2 for h/T/S'). All GEMM weights LDS-staged;
// every kernel sized for 4 blocks/CU except K2f (50.2 KB -> 3/CU).
//   K1: h = x @ W_lin[:, :128].T + b_lin + t*W_lin[:,128]       (37.8 KB)
//   K2f: binary: A=h@Wb1L.T, Bb=h@Wb1R.T+bb1 (LDS only);
//          U=exp2(kA), V=exp2(kBb); S'=(63-2*sum_{i!=j}rcp(U_j V_i+1))/64
//        unary: T = tanh(h@Wu1.T + bu1)                          (50.2 KB)
//   K4: out = T@Wu2.T + S'@Wb2.T + bu2 + (63/64)*bb2; wt buffer restaged
//       between the T-pass (Wu2 rows) and S'-pass (Wb2 rows)     (37.8 KB)
#define LS 132  // LDS row stride (dwords): (4l)%32 -> 8 dwords/bank for b128
#define USTR 20 // U/V row stride: (20l)%32 -> 8 dwords/bank
#define ROW_ELEMS 524288  // 4096*128
#define EXPC 2.8853900817779268f  // 2*log2(e)

__device__ __forceinline__ float tanh_fast(float x) {
    float e = __builtin_amdgcn_exp2f(x * EXPC);
    return 1.0f - 2.0f * __builtin_amdgcn_rcpf(e + 1.0f);
}

__device__ __forceinline__ void stage64(const float* __restrict__ X, int r0,
                                        float* __restrict__ xs, int tid) {
    const float4* src = reinterpret_cast<const float4*>(X + (size_t)r0 * 128);
#pragma unroll
    for (int p = 0; p < 8; ++p) {
        const int q = p * 256 + tid;  // 2048 float4s
        const int r = q >> 5;
        const int k4 = (q & 31) << 2;
        *reinterpret_cast<float4*>(&xs[r * LS + k4]) = src[q];
    }
}

template <int NC>
__device__ __forceinline__ void accum_lds(const float* __restrict__ xs,
                                          const float* __restrict__ wt,
                                          int lane, int wc0,
                                          float (&acc)[NC]) {
#pragma unroll 8
    for (int kq = 0; kq < 32; ++kq) {
        const float4 a =
            *reinterpret_cast<const float4*>(&xs[lane * LS + kq * 4]);
#pragma unroll
        for (int c = 0; c < NC; ++c) {
            const float4 w = *reinterpret_cast<const float4*>(
                &wt[(wc0 + c) * 128 + kq * 4]);
            acc[c] = fmaf(a.x, w.x, acc[c]);
            acc[c] = fmaf(a.y, w.y, acc[c]);
            acc[c] = fmaf(a.z, w.z, acc[c]);
            acc[c] = fmaf(a.w, w.w, acc[c]);
        }
    }
}

// K1: h = x@W_lin[:,:128].T + b_lin + t*W_lin[:,128]. grid (64,16):
// bx = graph, 8 cols/block (2/wave). LDS 37.8 KB -> 4 blocks/CU.
__global__ __launch_bounds__(256) void k1_h(const float* __restrict__ x,
                                            const float* __restrict__ W_lin,
                                            const float* __restrict__ b_lin,
                                            const float* __restrict__ tp,
                                            float* __restrict__ h) {
    __shared__ float xs[64 * LS];
    __shared__ float wt[8 * 128];
    const int tid = threadIdx.x;
    const int lane = tid & 63;
    const int wv = __builtin_amdgcn_readfirstlane(tid >> 6);
    const int r0 = blockIdx.x * 64;       // graph
    const int cb = blockIdx.y * 8;        // col base
    stage64(x, r0, xs, tid);
#pragma unroll
    for (int p = 0; p < 4; ++p) {         // 1024 floats = 8 rows x 128
        const int q = p * 256 + tid;
        const int row = q >> 7;
        const int col = q & 127;
        wt[row * 128 + col] = W_lin[(cb + row) * 129 + col];
    }
    __syncthreads();
    float acc[2] = {0.f, 0.f};
    accum_lds<2>(xs, wt, lane, wv * 2, acc);
    const int c0 = cb + wv * 2;
    const float tv = tp[0];
    float2 o;
    o.x = acc[0] + b_lin[c0 + 0] + tv * W_lin[(c0 + 0) * 129 + 128];
    o.y = acc[1] + b_lin[c0 + 1] + tv * W_lin[(c0 + 1) * 129 + 128];
    *reinterpret_cast<float2*>(&h[(size_t)(r0 + lane) * 128 + c0]) = o;
}

// K2f: grid (64, 12): bx = graph. by < 8 -> binary chunk of 16 channels;
// by >= 8 -> unary T cols (32/block, 8/wave). LDS 50.2 KB -> 3 blocks/CU.
__global__ __launch_bounds__(256) void k2_fused(
    const float* __restrict__ h, const float* __restrict__ Wu1,
    const float* __restrict__ bu1, const float* __restrict__ Wb1,
    const float* __restrict__ bb1, float* __restrict__ T,
    float* __restrict__ S) {
    __shared__ float smem[64 * LS + 32 * 128];
    float* xs = smem;
    float* wt = smem + 64 * LS;
    float* us = smem;              // alias: xs region (dead after GEMM)
    float* vs = smem + 64 * USTR;
    const int tid = threadIdx.x;
    const int lane = tid & 63;
    const int wv = __builtin_amdgcn_readfirstlane(tid >> 6);
    const int r0 = blockIdx.x * 64;  // graph * 64
    const int j = blockIdx.y;        // role 0..11
    stage64(h, r0, xs, tid);
    {   // Stage 32 weight rows (binary: 16 A-rows + 16 B-rows; unary: 32 Wu1)
        const int cb = j < 8 ? j * 16 : 0;
        const int cg0 = j >= 8 ? (j - 8) * 32 : 0;
#pragma unroll
        for (int p = 0; p < 4; ++p) {
            const int q = p * 256 + tid;  // 1024 float4s
            const int row = q >> 5;
            const int k4 = (q & 31) << 2;
            const float* src;
            if (j < 8)
                src = (row < 16) ? (Wb1 + (cb + row) * 256 + k4)
                                 : (Wb1 + (cb + row - 16) * 256 + 128 + k4);
            else
                src = Wu1 + (cg0 + row) * 128 + k4;
            *reinterpret_cast<float4*>(&wt[row * 128 + k4]) =
                *reinterpret_cast<const float4*>(src);
        }
    }
    __syncthreads();

    if (j < 8) {  // ---- binary chunk ----
        const int cb = j * 16;
        const bool isB = wv >= 2;
        const int half = wv & 1;
        const int c0 = cb + half * 8;
        const int wc0 = (isB ? 16 : 0) + half * 8;
        float acc[8] = {0.f, 0.f, 0.f, 0.f, 0.f, 0.f, 0.f, 0.f};
        accum_lds<8>(xs, wt, lane, wc0, acc);
        float e[8];
#pragma unroll
        for (int c = 0; c < 8; ++c) {
            const float v = isB ? (acc[c] + bb1[c0 + c]) : acc[c];
            e[c] = __builtin_amdgcn_exp2f(v * EXPC);
        }
        __syncthreads();  // all waves done reading xs; safe to overwrite
        float* dstl = (isB ? vs : us) + lane * USTR + half * 8;
        *reinterpret_cast<float4*>(dstl) = make_float4(e[0], e[1], e[2], e[3]);
        *reinterpret_cast<float4*>(dstl + 4) =
            make_float4(e[4], e[5], e[6], e[7]);
        __syncthreads();

        const int lc = wv * 4;
        const float4 u =
            *reinterpret_cast<const float4*>(&us[lane * USTR + lc]);
        float s0 = 0.f, s1 = 0.f, s2 = 0.f, s3 = 0.f;
#pragma unroll 8
        for (int i = 0; i < 64; ++i) {
            const float4 v =
                *reinterpret_cast<const float4*>(&vs[i * USTR + lc]);
            s0 += __builtin_amdgcn_rcpf(fmaf(u.x, v.x, 1.0f));
            s1 += __builtin_amdgcn_rcpf(fmaf(u.y, v.y, 1.0f));
            s2 += __builtin_amdgcn_rcpf(fmaf(u.z, v.z, 1.0f));
            s3 += __builtin_amdgcn_rcpf(fmaf(u.w, v.w, 1.0f));
        }
        const float4 vj =
            *reinterpret_cast<const float4*>(&vs[lane * USTR + lc]);
        float4 o;
        o.x = (63.0f - 2.0f * (s0 - __builtin_amdgcn_rcpf(fmaf(u.x, vj.x, 1.0f)))) * 0.015625f;
        o.y = (63.0f - 2.0f * (s1 - __builtin_amdgcn_rcpf(fmaf(u.y, vj.y, 1.0f)))) * 0.015625f;
        o.z = (63.0f - 2.0f * (s2 - __builtin_amdgcn_rcpf(fmaf(u.z, vj.z, 1.0f)))) * 0.015625f;
        o.w = (63.0f - 2.0f * (s3 - __builtin_amdgcn_rcpf(fmaf(u.w, vj.w, 1.0f)))) * 0.015625f;
        *reinterpret_cast<float4*>(&S[(size_t)(r0 + lane) * 128 + cb + lc]) = o;
    } else {  // ---- unary T ----
        const int c0 = (j - 8) * 32 + wv * 8;
        float acc[8] = {0.f, 0.f, 0.f, 0.f, 0.f, 0.f, 0.f, 0.f};
        accum_lds<8>(xs, wt, lane, wv * 8, acc);
        float4 v0, v1;
        v0.x = tanh_fast(acc[0] + bu1[c0 + 0]);
        v0.y = tanh_fast(acc[1] + bu1[c0 + 1]);
        v0.z = tanh_fast(acc[2] + bu1[c0 + 2]);
        v0.w = tanh_fast(acc[3] + bu1[c0 + 3]);
        v1.x = tanh_fast(acc[4] + bu1[c0 + 4]);
        v1.y = tanh_fast(acc[5] + bu1[c0 + 5]);
        v1.z = tanh_fast(acc[6] + bu1[c0 + 6]);
        v1.w = tanh_fast(acc[7] + bu1[c0 + 7]);
        float* dst = T + (size_t)(r0 + lane) * 128 + c0;
        *reinterpret_cast<float4*>(dst) = v0;
        *reinterpret_cast<float4*>(dst + 4) = v1;
    }
}

// K4: out = T@Wu2.T + S'@Wb2.T + bu2 + (63/64)*bb2. grid (64,16):
// bx = graph, 8 cols/block (2/wave). wt = 4 KB, restaged between passes
// (Wu2 rows for the T-pass, Wb2 rows for the S'-pass). LDS 37.8 KB ->
// 4 blocks/CU (all 1024 blocks resident).
__global__ __launch_bounds__(256) void k4_out(
    const float* __restrict__ T, const float* __restrict__ S,
    const float* __restrict__ Wu2, const float* __restrict__ Wb2,
    const float* __restrict__ bu2, const float* __restrict__ bb2,
    float* __restrict__ out) {
    __shared__ float xs[64 * LS];
    __shared__ float wt[8 * 128];
    const int tid = threadIdx.x;
    const int lane = tid & 63;
    const int wv = __builtin_amdgcn_readfirstlane(tid >> 6);
    const int r0 = blockIdx.x * 64;
    const int cb = blockIdx.y * 8;
    // Pass 1: T x Wu2
    stage64(T, r0, xs, tid);
    {   // 8 rows x 128 = 256 float4s, 1 per thread
        const int row = tid >> 5;
        const int k4 = (tid & 31) << 2;
        *reinterpret_cast<float4*>(&wt[row * 128 + k4]) =
            *reinterpret_cast<const float4*>(Wu2 + (cb + row) * 128 + k4);
    }
    __syncthreads();
    float acc[2] = {0.f, 0.f};
    accum_lds<2>(xs, wt, lane, wv * 2, acc);
    __syncthreads();  // done reading T tile + Wu2 wt
    // Pass 2: S' x Wb2 (restage both buffers)
    stage64(S, r0, xs, tid);
    {
        const int row = tid >> 5;
        const int k4 = (tid & 31) << 2;
        *reinterpret_cast<float4*>(&wt[row * 128 + k4]) =
            *reinterpret_cast<const float4*>(Wb2 + (cb + row) * 128 + k4);
    }
    __syncthreads();
    accum_lds<2>(xs, wt, lane, wv * 2, acc);
    const int c0 = cb + wv * 2;
    float2 o;
    o.x = acc[0] + bu2[c0 + 0] + 0.984375f * bb2[c0 + 0];
    o.y = acc[1] + bu2[c0 + 1] + 0.984375f * bb2[c0 + 1];
    *reinterpret_cast<float2*>(&out[(size_t)(r0 + lane) * 128 + c0]) = o;
}

extern "C" void kernel_launch(void* const* d_in, const int* in_sizes, int n_in,
                              void* d_out, int out_size, void* d_ws,
                              size_t ws_size, hipStream_t stream) {
    const float* t = (const float*)d_in[0];
    const float* x = (const float*)d_in[1];
    const float* W_lin = (const float*)d_in[2];
    const float* b_lin = (const float*)d_in[3];
    const float* Wu1 = (const float*)d_in[4];
    const float* bu1 = (const float*)d_in[5];
    const float* Wu2 = (const float*)d_in[6];
    const float* bu2 = (const float*)d_in[7];
    const float* Wb1 = (const float*)d_in[8];
    const float* bb1 = (const float*)d_in[9];
    const float* Wb2 = (const float*)d_in[10];
    const float* bb2 = (const float*)d_in[11];
    float* out = (float*)d_out;

    float* ws = (float*)d_ws;
    float* h = ws;
    float* T = ws + 1 * ROW_ELEMS;
    float* S = ws + 2 * ROW_ELEMS;

    // All grids: blockIdx.x = graph -> linear_id % 8 == graph % 8 (XCD-local).
    k1_h<<<dim3(64, 16), 256, 0, stream>>>(x, W_lin, b_lin, t, h);
    k2_fused<<<dim3(64, 12), 256, 0, stream>>>(h, Wu1, bu1, Wb1, bb1, T, S);
    k4_out<<<dim3(64, 16), 256, 0, stream>>>(T, S, Wu2, Wb2, bu2, bb2, out);
    (void)in_sizes; (void)n_in; (void)out_size; (void)ws_size;
}

// Round 12
// 33.512 us; speedup vs baseline: 3.0241x; 1.1150x over previous
//
#include <hip/hip_runtime.h>

// Problem: N=64 graphs, K=64 nodes, C_IN=128, C=128, fp32.
// Weight-composition pipeline (3 kernels; K1 eliminated algebraically):
//   K0: composites WcU=Wu1@Wl, WcA=Wb1L@Wl, WcB=Wb1R@Wl (Wl = W_lin[:,:128])
//       and biases bU=bu1+Wu1@hb, bA=Wb1L@hb, bB=bb1+Wb1R@hb,
//       hb = b_lin + t*W_lin[:,128].  (6.3M MAC, 96 blocks)
//   K2f (reads x directly): binary: A=x@WcA.T+bA, Bb=x@WcB.T+bB (LDS only);
//          U=exp2(kA), V=exp2(kBb); S'=(63-2*sum_{i!=j}rcp(U_j V_i+1))/64
//        unary: T = tanh(x@WcU.T + bU)
//   K4: out = T@Wu2.T + S'@Wb2.T + bu2 + (63/64)*bb2   (R8-exact, s_load)
// XCD-local: blockIdx.x = graph in K2f/K4 -> linear_id%8 == g%8, so all
// blocks of a graph share one XCD's L2 for x/T/S'.
#define LS 132  // LDS row stride (dwords): (4l)%32 -> 8 dwords/bank for b128
#define USTR 20 // U/V row stride: (20l)%32 -> 8 dwords/bank
#define ROW_ELEMS 524288  // 4096*128
#define EXPC 2.8853900817779268f  // 2*log2(e)

__device__ __forceinline__ float tanh_fast(float x) {
    float e = __builtin_amdgcn_exp2f(x * EXPC);
    return 1.0f - 2.0f * __builtin_amdgcn_rcpf(e + 1.0f);
}

__device__ __forceinline__ void stage64(const float* __restrict__ X, int r0,
                                        float* __restrict__ xs, int tid) {
    const float4* src = reinterpret_cast<const float4*>(X + (size_t)r0 * 128);
#pragma unroll
    for (int p = 0; p < 8; ++p) {
        const int q = p * 256 + tid;  // 2048 float4s
        const int r = q >> 5;
        const int k4 = (q & 31) << 2;
        *reinterpret_cast<float4*>(&xs[r * LS + k4]) = src[q];
    }
}

template <int NC>
__device__ __forceinline__ void accum_lds(const float* __restrict__ xs,
                                          const float* __restrict__ wt,
                                          int lane, int wc0,
                                          float (&acc)[NC]) {
#pragma unroll 8
    for (int kq = 0; kq < 32; ++kq) {
        const float4 a =
            *reinterpret_cast<const float4*>(&xs[lane * LS + kq * 4]);
#pragma unroll
        for (int c = 0; c < NC; ++c) {
            const float4 w = *reinterpret_cast<const float4*>(
                &wt[(wc0 + c) * 128 + kq * 4]);
            acc[c] = fmaf(a.x, w.x, acc[c]);
            acc[c] = fmaf(a.y, w.y, acc[c]);
            acc[c] = fmaf(a.z, w.z, acc[c]);
            acc[c] = fmaf(a.w, w.w, acc[c]);
        }
    }
}

// K0: composite weights + biases. grid 96 blocks x 256 thr.
// Block bid: comp = bid>>5 (0=U,1=A,2=B), rows (bid&31)*4 .. +3 (1 per wave).
// Wc[comp][r][d] = sum_e W2[r][e] * W_lin[e*129 + d]  (d via lane, lane+64)
// bias[comp][r]  = base + sum_e W2[r][e] * hb[e]
__global__ __launch_bounds__(256) void k0_comp(
    const float* __restrict__ W_lin, const float* __restrict__ b_lin,
    const float* __restrict__ Wu1, const float* __restrict__ bu1,
    const float* __restrict__ Wb1, const float* __restrict__ bb1,
    const float* __restrict__ tp, float* __restrict__ Wc,
    float* __restrict__ bias) {
    const int tid = threadIdx.x;
    const int lane = tid & 63;
    const int wv = __builtin_amdgcn_readfirstlane(tid >> 6);
    const int bid = blockIdx.x;
    const int comp = bid >> 5;           // 0,1,2
    const int r = (bid & 31) * 4 + wv;   // row 0..127 within composite
    const float* w2;
    if (comp == 0)
        w2 = Wu1 + r * 128;
    else if (comp == 1)
        w2 = Wb1 + r * 256;        // left half
    else
        w2 = Wb1 + r * 256 + 128;  // right half

    float a0 = 0.f, a1 = 0.f;
#pragma unroll 8
    for (int e = 0; e < 128; ++e) {
        const float w2e = w2[e];  // wave-uniform -> s_load
        a0 = fmaf(w2e, W_lin[e * 129 + lane], a0);
        a1 = fmaf(w2e, W_lin[e * 129 + lane + 64], a1);
    }
    Wc[comp * 16384 + r * 128 + lane] = a0;
    Wc[comp * 16384 + r * 128 + lane + 64] = a1;

    // bias: pb = sum over this lane's two e-slots, then wave-reduce.
    const float tv = tp[0];
    const float hb0 = b_lin[lane] + tv * W_lin[lane * 129 + 128];
    const float hb1 = b_lin[lane + 64] + tv * W_lin[(lane + 64) * 129 + 128];
    float pb = w2[lane] * hb0 + w2[lane + 64] * hb1;
#pragma unroll
    for (int m = 32; m >= 1; m >>= 1) pb += __shfl_xor(pb, m, 64);
    if (lane == 0) {
        float base = 0.f;
        if (comp == 0) base = bu1[r];
        else if (comp == 2) base = bb1[r];
        bias[comp * 128 + r] = pb + base;
    }
}

// K2f: grid (64, 12): bx = graph. by < 8 -> binary chunk of 16 channels;
// by >= 8 -> unary T cols (32/block, 8/wave). LDS 50.2 KB -> 3 blocks/CU.
// Reads x directly with composite weights/biases from K0.
__global__ __launch_bounds__(256) void k2_fused(
    const float* __restrict__ x, const float* __restrict__ Wc,
    const float* __restrict__ bias, float* __restrict__ T,
    float* __restrict__ S) {
    __shared__ float smem[64 * LS + 32 * 128];
    float* xs = smem;
    float* wt = smem + 64 * LS;
    float* us = smem;              // alias: xs region (dead after GEMM)
    float* vs = smem + 64 * USTR;
    const float* WcU = Wc;
    const float* WcA = Wc + 16384;
    const float* WcB = Wc + 32768;
    const float* bU = bias;
    const float* bA = bias + 128;
    const float* bB = bias + 256;
    const int tid = threadIdx.x;
    const int lane = tid & 63;
    const int wv = __builtin_amdgcn_readfirstlane(tid >> 6);
    const int r0 = blockIdx.x * 64;  // graph * 64
    const int j = blockIdx.y;        // role 0..11
    stage64(x, r0, xs, tid);
    {   // Stage 32 weight rows (binary: 16 WcA + 16 WcB; unary: 32 WcU)
        const int cb = j < 8 ? j * 16 : 0;
        const int cg0 = j >= 8 ? (j - 8) * 32 : 0;
#pragma unroll
        for (int p = 0; p < 4; ++p) {
            const int q = p * 256 + tid;  // 1024 float4s
            const int row = q >> 5;
            const int k4 = (q & 31) << 2;
            const float* src;
            if (j < 8)
                src = (row < 16) ? (WcA + (cb + row) * 128 + k4)
                                 : (WcB + (cb + row - 16) * 128 + k4);
            else
                src = WcU + (cg0 + row) * 128 + k4;
            *reinterpret_cast<float4*>(&wt[row * 128 + k4]) =
                *reinterpret_cast<const float4*>(src);
        }
    }
    __syncthreads();

    if (j < 8) {  // ---- binary chunk ----
        const int cb = j * 16;
        const bool isB = wv >= 2;
        const int half = wv & 1;
        const int c0 = cb + half * 8;
        const int wc0 = (isB ? 16 : 0) + half * 8;
        float acc[8] = {0.f, 0.f, 0.f, 0.f, 0.f, 0.f, 0.f, 0.f};
        accum_lds<8>(xs, wt, lane, wc0, acc);
        float e[8];
#pragma unroll
        for (int c = 0; c < 8; ++c) {
            const float v = acc[c] + (isB ? bB[c0 + c] : bA[c0 + c]);
            e[c] = __builtin_amdgcn_exp2f(v * EXPC);
        }
        __syncthreads();  // all waves done reading xs; safe to overwrite
        float* dstl = (isB ? vs : us) + lane * USTR + half * 8;
        *reinterpret_cast<float4*>(dstl) = make_float4(e[0], e[1], e[2], e[3]);
        *reinterpret_cast<float4*>(dstl + 4) =
            make_float4(e[4], e[5], e[6], e[7]);
        __syncthreads();

        const int lc = wv * 4;
        const float4 u =
            *reinterpret_cast<const float4*>(&us[lane * USTR + lc]);
        float s0 = 0.f, s1 = 0.f, s2 = 0.f, s3 = 0.f;
#pragma unroll 8
        for (int i = 0; i < 64; ++i) {
            const float4 v =
                *reinterpret_cast<const float4*>(&vs[i * USTR + lc]);
            s0 += __builtin_amdgcn_rcpf(fmaf(u.x, v.x, 1.0f));
            s1 += __builtin_amdgcn_rcpf(fmaf(u.y, v.y, 1.0f));
            s2 += __builtin_amdgcn_rcpf(fmaf(u.z, v.z, 1.0f));
            s3 += __builtin_amdgcn_rcpf(fmaf(u.w, v.w, 1.0f));
        }
        const float4 vj =
            *reinterpret_cast<const float4*>(&vs[lane * USTR + lc]);
        float4 o;
        o.x = (63.0f - 2.0f * (s0 - __builtin_amdgcn_rcpf(fmaf(u.x, vj.x, 1.0f)))) * 0.015625f;
        o.y = (63.0f - 2.0f * (s1 - __builtin_amdgcn_rcpf(fmaf(u.y, vj.y, 1.0f)))) * 0.015625f;
        o.z = (63.0f - 2.0f * (s2 - __builtin_amdgcn_rcpf(fmaf(u.z, vj.z, 1.0f)))) * 0.015625f;
        o.w = (63.0f - 2.0f * (s3 - __builtin_amdgcn_rcpf(fmaf(u.w, vj.w, 1.0f)))) * 0.015625f;
        *reinterpret_cast<float4*>(&S[(size_t)(r0 + lane) * 128 + cb + lc]) = o;
    } else {  // ---- unary T ----
        const int c0 = (j - 8) * 32 + wv * 8;
        float acc[8] = {0.f, 0.f, 0.f, 0.f, 0.f, 0.f, 0.f, 0.f};
        accum_lds<8>(xs, wt, lane, wv * 8, acc);
        float4 v0, v1;
        v0.x = tanh_fast(acc[0] + bU[c0 + 0]);
        v0.y = tanh_fast(acc[1] + bU[c0 + 1]);
        v0.z = tanh_fast(acc[2] + bU[c0 + 2]);
        v0.w = tanh_fast(acc[3] + bU[c0 + 3]);
        v1.x = tanh_fast(acc[4] + bU[c0 + 4]);
        v1.y = tanh_fast(acc[5] + bU[c0 + 5]);
        v1.z = tanh_fast(acc[6] + bU[c0 + 6]);
        v1.w = tanh_fast(acc[7] + bU[c0 + 7]);
        float* dst = T + (size_t)(r0 + lane) * 128 + c0;
        *reinterpret_cast<float4*>(dst) = v0;
        *reinterpret_cast<float4*>(dst + 4) = v1;
    }
}

// K4: out = T@Wu2.T + S'@Wb2.T + bu2 + (63/64)*bb2. grid (64,16):
// bx = graph (XCD-local T/S' reads). Two 128-k passes over one xs tile,
// s_load weights (2 streams/wave -> SGPR-friendly). 34.8 KB -> 4 blocks/CU.
__global__ __launch_bounds__(256) void k4_out(
    const float* __restrict__ T, const float* __restrict__ S,
    const float* __restrict__ Wu2, const float* __restrict__ Wb2,
    const float* __restrict__ bu2, const float* __restrict__ bb2,
    float* __restrict__ out) {
    __shared__ float xs[64 * LS];
    const int tid = threadIdx.x;
    const int lane = tid & 63;
    const int wv = __builtin_amdgcn_readfirstlane(tid >> 6);
    const int r0 = blockIdx.x * 64;
    const int c0 = blockIdx.y * 8 + wv * 2;
    stage64(T, r0, xs, tid);
    __syncthreads();
    float acc[2] = {0.f, 0.f};
    {
        const float* w0 = Wu2 + (c0 + 0) * 128;
        const float* w1 = Wu2 + (c0 + 1) * 128;
#pragma unroll 8
        for (int kq = 0; kq < 32; ++kq) {
            const float4 a =
                *reinterpret_cast<const float4*>(&xs[lane * LS + kq * 4]);
            acc[0] = fmaf(a.x, w0[kq * 4 + 0], acc[0]);
            acc[0] = fmaf(a.y, w0[kq * 4 + 1], acc[0]);
            acc[0] = fmaf(a.z, w0[kq * 4 + 2], acc[0]);
            acc[0] = fmaf(a.w, w0[kq * 4 + 3], acc[0]);
            acc[1] = fmaf(a.x, w1[kq * 4 + 0], acc[1]);
            acc[1] = fmaf(a.y, w1[kq * 4 + 1], acc[1]);
            acc[1] = fmaf(a.z, w1[kq * 4 + 2], acc[1]);
            acc[1] = fmaf(a.w, w1[kq * 4 + 3], acc[1]);
        }
    }
    __syncthreads();
    stage64(S, r0, xs, tid);
    __syncthreads();
    {
        const float* w0 = Wb2 + (c0 + 0) * 128;
        const float* w1 = Wb2 + (c0 + 1) * 128;
#pragma unroll 8
        for (int kq = 0; kq < 32; ++kq) {
            const float4 a =
                *reinterpret_cast<const float4*>(&xs[lane * LS + kq * 4]);
            acc[0] = fmaf(a.x, w0[kq * 4 + 0], acc[0]);
            acc[0] = fmaf(a.y, w0[kq * 4 + 1], acc[0]);
            acc[0] = fmaf(a.z, w0[kq * 4 + 2], acc[0]);
            acc[0] = fmaf(a.w, w0[kq * 4 + 3], acc[0]);
            acc[1] = fmaf(a.x, w1[kq * 4 + 0], acc[1]);
            acc[1] = fmaf(a.y, w1[kq * 4 + 1], acc[1]);
            acc[1] = fmaf(a.z, w1[kq * 4 + 2], acc[1]);
            acc[1] = fmaf(a.w, w1[kq * 4 + 3], acc[1]);
        }
    }
    float2 o;
    o.x = acc[0] + bu2[c0 + 0] + 0.984375f * bb2[c0 + 0];
    o.y = acc[1] + bu2[c0 + 1] + 0.984375f * bb2[c0 + 1];
    *reinterpret_cast<float2*>(&out[(size_t)(r0 + lane) * 128 + c0]) = o;
}

extern "C" void kernel_launch(void* const* d_in, const int* in_sizes, int n_in,
                              void* d_out, int out_size, void* d_ws,
                              size_t ws_size, hipStream_t stream) {
    const float* t = (const float*)d_in[0];
    const float* x = (const float*)d_in[1];
    const float* W_lin = (const float*)d_in[2];
    const float* b_lin = (const float*)d_in[3];
    const float* Wu1 = (const float*)d_in[4];
    const float* bu1 = (const float*)d_in[5];
    const float* Wu2 = (const float*)d_in[6];
    const float* bu2 = (const float*)d_in[7];
    const float* Wb1 = (const float*)d_in[8];
    const float* bb1 = (const float*)d_in[9];
    const float* Wb2 = (const float*)d_in[10];
    const float* bb2 = (const float*)d_in[11];
    float* out = (float*)d_out;

    float* ws = (float*)d_ws;
    float* Wc = ws;                   // 3 * 16384 composite weights
    float* bias = ws + 49152;         // 3 * 128 composite biases
    float* T = ws + 1 * ROW_ELEMS;    // [4096,128]
    float* S = ws + 2 * ROW_ELEMS;    // [4096,128] (pre-scaled by 1/64)

    // K0: composites (96 blocks, ~6.3M MAC)
    k0_comp<<<96, 256, 0, stream>>>(W_lin, b_lin, Wu1, bu1, Wb1, bb1, t, Wc,
                                    bias);
    // K2f: S' + T from x directly (768 blocks, XCD-local by graph)
    k2_fused<<<dim3(64, 12), 256, 0, stream>>>(x, Wc, bias, T, S);
    // K4: out (1024 blocks, XCD-local by graph)
    k4_out<<<dim3(64, 16), 256, 0, stream>>>(T, S, Wu2, Wb2, bu2, bb2, out);
    (void)in_sizes; (void)n_in; (void)out_size; (void)ws_size;
}